// Round 4
// baseline (292.909 us; speedup 1.0000x reference)
//
#include <hip/hip_runtime.h>
#include <hip/hip_bf16.h>

#define EPS 1e-5f

typedef short bf16x8 __attribute__((ext_vector_type(8)));
typedef float f32x4 __attribute__((ext_vector_type(4)));

#define GL16(gp, lp) __builtin_amdgcn_global_load_lds( \
    (const __attribute__((address_space(1))) void*)(gp), \
    (__attribute__((address_space(3))) void*)(lp), 16, 0, 0)

__device__ __forceinline__ unsigned short f2bf(float f) {
  union { float f; unsigned u; } v; v.f = f;
  return (unsigned short)((v.u + 0x7FFFu + ((v.u >> 16) & 1u)) >> 16);
}

// ---------------- fp32 -> bf16 convert, 3 tensors in one launch ----------------
__global__ void cvt3_kernel(const float* __restrict__ s0, const float* __restrict__ s1,
                            const float* __restrict__ s2,
                            unsigned short* __restrict__ d0, unsigned short* __restrict__ d1,
                            unsigned short* __restrict__ d2) {
  const float* src = blockIdx.y == 0 ? s0 : (blockIdx.y == 1 ? s1 : s2);
  unsigned short* dst = blockIdx.y == 0 ? d0 : (blockIdx.y == 1 ? d1 : d2);
  int i = (blockIdx.x * blockDim.x + threadIdx.x) * 8;
  float4 a = *(const float4*)(src + i);
  float4 b = *(const float4*)(src + i + 4);
  union { bf16x8 v; unsigned short u[8]; } o;
  o.u[0] = f2bf(a.x); o.u[1] = f2bf(a.y); o.u[2] = f2bf(a.z); o.u[3] = f2bf(a.w);
  o.u[4] = f2bf(b.x); o.u[5] = f2bf(b.y); o.u[6] = f2bf(b.z); o.u[7] = f2bf(b.w);
  *(bf16x8*)(dst + i) = o.v;
}

// ---------------- 4 weight transposes (K x N fp32 -> N x K bf16) in one launch ----------------
__global__ void wtrans4_kernel(const float* __restrict__ W0, const float* __restrict__ W1,
                               const float* __restrict__ W2, const float* __restrict__ W3,
                               unsigned short* __restrict__ T0, unsigned short* __restrict__ T1,
                               unsigned short* __restrict__ T2, unsigned short* __restrict__ T3) {
  __shared__ float tile[32][33];
  int z = blockIdx.z;
  const float* W = z == 0 ? W0 : z == 1 ? W1 : z == 2 ? W2 : W3;
  unsigned short* Wt = z == 0 ? T0 : z == 1 ? T1 : z == 2 ? T2 : T3;
  float scale = (z == 0) ? 0.125f : 1.0f;   // fold 1/sqrt(64) into Wq
  int n0 = blockIdx.x * 32, k0 = blockIdx.y * 32;
  int c = threadIdx.x & 31, r0 = threadIdx.x >> 5;
  #pragma unroll
  for (int rr = 0; rr < 32; rr += 8)
    tile[r0 + rr][c] = W[(k0 + r0 + rr) * 512 + n0 + c];
  __syncthreads();
  #pragma unroll
  for (int rr = 0; rr < 32; rr += 8)
    Wt[(n0 + r0 + rr) * 512 + k0 + c] = f2bf(tile[c][r0 + rr] * scale);
}

// ---------------- per-(b,q) stoich row stats: sum(P), sum(N), sum(P^2), sum(N^2) ----------------
__global__ void frac_stats_kernel(const float* __restrict__ frac,
                                  float* __restrict__ fstats) {
  int wid = (int)((blockIdx.x * blockDim.x + threadIdx.x) >> 6);
  int ln = threadIdx.x & 63;
  if (wid >= 8192) return;
  int b = wid >> 10, q = wid & 1023;
  const float* fr = frac + b * 1024;
  float fq = fr[q];
  float sp = 0.f, sn = 0.f, sp2 = 0.f, sn2 = 0.f;
  for (int i = ln; i < 1024; i += 64) {
    float f = fr[i];
    float dm = (f - fq) * (fq * f);
    float p = fmaxf(dm, 0.f), nn = fminf(dm, 0.f);
    sp += p; sn += nn; sp2 += p * p; sn2 += nn * nn;
  }
  #pragma unroll
  for (int m = 32; m; m >>= 1) {
    sp += __shfl_xor(sp, m); sn += __shfl_xor(sn, m);
    sp2 += __shfl_xor(sp2, m); sn2 += __shfl_xor(sn2, m);
  }
  if (ln == 0) {
    float4 o; o.x = sp; o.y = sn; o.z = sp2; o.w = sn2;
    *(float4*)(fstats + (size_t)wid * 4) = o;
  }
}

// ---------------- bf16 MFMA GEMM:  C(M x 512) = A(M x 512) * W^T(rows=n)  + bias ----------------
template <int MODE>
__global__ __launch_bounds__(256) void gemm_kernel(
    const unsigned short* __restrict__ A,
    const unsigned short* __restrict__ Bt,
    const float* __restrict__ bias, float bscale,
    void* __restrict__ out) {
  __shared__ unsigned short Al[2][128 * 32];
  __shared__ unsigned short Bl[2][128 * 32];
  const int tid = threadIdx.x, ln = tid & 63, wv = tid >> 6;
  const int m0 = blockIdx.y * 128, n0 = blockIdx.x * 128;
  const int wr = wv >> 1, wc = wv & 1;

  auto stage = [&](int kt, int buf) {
    int kb = kt * 32;
    #pragma unroll
    for (int u = 0; u < 2; ++u) {
      int n = tid + u * 256;
      int Lrow = n >> 2, kcs = n & 3;
      int kc = kcs ^ (Lrow & 3);
      GL16(A + (size_t)(m0 + Lrow) * 512 + kb + kc * 8, &Al[buf][n * 8]);
      GL16(Bt + (size_t)(n0 + Lrow) * 512 + kb + kc * 8, &Bl[buf][n * 8]);
    }
  };

  f32x4 acc[4][4] = {};
  stage(0, 0);
  for (int kt = 0; kt < 16; ++kt) {
    __syncthreads();
    if (kt < 15) stage(kt + 1, (kt + 1) & 1);
    const unsigned short* a_ = Al[kt & 1];
    const unsigned short* b_ = Bl[kt & 1];
    const int kc = ln >> 4;
    bf16x8 afr[4], bfr[4];
    #pragma unroll
    for (int m = 0; m < 4; ++m) {
      int r = wr * 64 + m * 16 + (ln & 15);
      afr[m] = *(const bf16x8*)(a_ + r * 32 + ((kc ^ (r & 3)) * 8));
    }
    #pragma unroll
    for (int n = 0; n < 4; ++n) {
      int r = wc * 64 + n * 16 + (ln & 15);
      bfr[n] = *(const bf16x8*)(b_ + r * 32 + ((kc ^ (r & 3)) * 8));
    }
    #pragma unroll
    for (int m = 0; m < 4; ++m)
      #pragma unroll
      for (int n = 0; n < 4; ++n)
        acc[m][n] = __builtin_amdgcn_mfma_f32_16x16x32_bf16(afr[m], bfr[n], acc[m][n], 0, 0, 0);
  }

  #pragma unroll
  for (int m = 0; m < 4; ++m) {
    #pragma unroll
    for (int n = 0; n < 4; ++n) {
      int gm0 = m0 + wr * 64 + m * 16 + (ln >> 4) * 4;
      int gn = n0 + wc * 64 + n * 16 + (ln & 15);
      float bvv = bias[gn] * bscale;
      if constexpr (MODE == 2) {
        float* o = (float*)out;
        #pragma unroll
        for (int i = 0; i < 4; ++i)
          o[(size_t)(gm0 + i) * 512 + gn] = acc[m][n][i] + bvv;
      } else if constexpr (MODE == 0) {
        unsigned short* o = (unsigned short*)out;
        int h = gn >> 6, d = gn & 63;
        #pragma unroll
        for (int i = 0; i < 4; ++i) {
          int gm = gm0 + i;
          int b = gm >> 10, t = gm & 1023;
          o[(size_t)((b * 8 + h) * 1024 + t) * 64 + d] = f2bf(acc[m][n][i] + bvv);
        }
      } else {  // MODE 1: V^T (b,h,d,t)
        unsigned short* o = (unsigned short*)out;
        int h = gn >> 6, d = gn & 63;
        int b = gm0 >> 10, t = gm0 & 1023;
        ushort4 pk;
        pk.x = f2bf(acc[m][n][0] + bvv);
        pk.y = f2bf(acc[m][n][1] + bvv);
        pk.z = f2bf(acc[m][n][2] + bvv);
        pk.w = f2bf(acc[m][n][3] + bvv);
        *(ushort4*)(o + (size_t)((b * 8 + h) * 64 + d) * 1024 + t) = pk;
      }
    }
  }
}

// ---------------- fused attention v4: 32 queries/block, ALL 16x16x32 MFMA ----------------
// Swapped QK^T (A=K, B=Q) -> S[key][query] register-resident per wave (128 keys).
// PV chains without LDS: free k-permutation sigma(key <-> (group,elem)) applied to
// both the P A-fragment (packed from S regs) and the V B-fragment (global loads).
__global__ __launch_bounds__(512, 4) void attn_kernel(
    const unsigned short* __restrict__ Qh,   // (b,h,t,d) bf16, pre-scaled by 1/8
    const unsigned short* __restrict__ Kh,   // (b,h,t,d) bf16
    const unsigned short* __restrict__ Vt,   // (b,h,d,t) bf16
    unsigned short* __restrict__ attnO,      // (b,t,h*64+d) bf16
    const float* __restrict__ frac,
    const float* __restrict__ fstats,
    const float* __restrict__ alpha_pos,
    const float* __restrict__ alpha_neg,
    const float* __restrict__ gamma_p,
    const float* __restrict__ delta_p,
    const int* __restrict__ afb_p) {
  __shared__ float fk[1024];
  __shared__ float Obuf[32][64];
  __shared__ float sumW[8][32];
  __shared__ float sumW2[8][32];
  __shared__ float sumP[8][32];
  __shared__ float4 rowc[32];
  __shared__ float rowRcp[32];

  // XCD-aware remap: XCD x owns 8 bh values (K/V ~2MB, L2-resident per XCD)
  const int L = blockIdx.x;
  const int slot = L >> 3;
  const int bh = (L & 7) + 8 * (slot >> 5);
  const int t0 = (slot & 31) * 32;
  const int b = bh >> 3, h = bh & 7;

  const int tid = threadIdx.x, ln = tid & 63, wv = tid >> 6;
  const int c = ln & 15, g = ln >> 4;

  fk[tid] = frac[b * 1024 + tid];
  fk[tid + 512] = frac[b * 1024 + 512 + tid];
  {
    float* ob = &Obuf[0][0];
    ob[tid] = 0.f; ob[tid + 512] = 0.f; ob[tid + 1024] = 0.f; ob[tid + 1536] = 0.f;
  }

  // Q B-fragments: lane(c,g) holds Q[t0+qt*16+c][kh*32 + g*8 + e]
  bf16x8 qf[2][2];
  #pragma unroll
  for (int qt = 0; qt < 2; ++qt) {
    const unsigned short* qrow = Qh + (size_t)(bh * 1024 + t0 + qt * 16 + c) * 64 + g * 8;
    qf[qt][0] = *(const bf16x8*)(qrow);
    qf[qt][1] = *(const bf16x8*)(qrow + 32);
  }

  // ---- QK^T swapped: S[kt][qt][reg] = scores[key = keyb+kt*16+g*4+reg][query = t0+qt*16+c]
  const int keyb = wv * 128;
  f32x4 S[8][2];
  #pragma unroll
  for (int kt = 0; kt < 8; ++kt) {
    const unsigned short* krow =
        Kh + (size_t)(bh * 1024 + keyb + kt * 16 + c) * 64 + g * 8;
    bf16x8 kf0 = *(const bf16x8*)(krow);
    bf16x8 kf1 = *(const bf16x8*)(krow + 32);
    #pragma unroll
    for (int qt = 0; qt < 2; ++qt) {
      f32x4 a = {0.f, 0.f, 0.f, 0.f};
      a = __builtin_amdgcn_mfma_f32_16x16x32_bf16(kf0, qf[qt][0], a, 0, 0, 0);
      a = __builtin_amdgcn_mfma_f32_16x16x32_bf16(kf1, qf[qt][1], a, 0, 0, 0);
      S[kt][qt] = a;
    }
  }

  // ---- logits row stats ----
  {
    float sL[2] = {0.f, 0.f}, sL2[2] = {0.f, 0.f};
    #pragma unroll
    for (int kt = 0; kt < 8; ++kt)
      #pragma unroll
      for (int qt = 0; qt < 2; ++qt)
        #pragma unroll
        for (int r = 0; r < 4; ++r) {
          float v = S[kt][qt][r];
          sL[qt] += v; sL2[qt] += v * v;
        }
    #pragma unroll
    for (int qt = 0; qt < 2; ++qt) {
      sL[qt] += __shfl_xor(sL[qt], 16);
      sL[qt] += __shfl_xor(sL[qt], 32);
      sL2[qt] += __shfl_xor(sL2[qt], 16);
      sL2[qt] += __shfl_xor(sL2[qt], 32);
      if (g == 0) { sumW[wv][qt * 16 + c] = sL[qt]; sumW2[wv][qt * 16 + c] = sL2[qt]; }
    }
  }
  __syncthreads();
  if (tid < 32) {
    float sl = 0.f, sl2 = 0.f;
    #pragma unroll
    for (int w = 0; w < 8; ++w) { sl += sumW[w][tid]; sl2 += sumW2[w][tid]; }
    float mul_ = sl * (1.f / 1024.f);
    float varl = fmaxf((sl2 - 1024.f * mul_ * mul_) * (1.f / 1023.f), 0.f);
    float cA = (*gamma_p) / (sqrtf(varl) + EPS);
    float ap = alpha_pos[h], an = alpha_neg[h];
    float4 st = *(const float4*)(fstats + (size_t)(b * 1024 + t0 + tid) * 4);
    float msum = ap * st.x + an * st.y;
    float msq = ap * ap * st.z + an * an * st.w;
    float mus = msum * (1.f / 1024.f);
    float vars = fmaxf((msq - 1024.f * mus * mus) * (1.f / 1023.f), 0.f);
    float cB = (*afb_p) ? ((*delta_p) / (sqrtf(vars) + EPS)) : 0.f;
    float4 rc;
    rc.x = frac[b * 1024 + t0 + tid];
    rc.y = cA;
    rc.z = cB;
    rc.w = cA * mul_ + cB * mus;   // shift (softmax-invariant)
    rowc[tid] = rc;
  }
  __syncthreads();

  // ---- exp in registers (overwrite S), psum ----
  {
    const float ap_ = alpha_pos[h], an_ = alpha_neg[h];
    const float4 rcq0 = rowc[c], rcq1 = rowc[16 + c];
    float psum[2] = {0.f, 0.f};
    #pragma unroll
    for (int qt = 0; qt < 2; ++qt) {
      const float4 rc = qt == 0 ? rcq0 : rcq1;
      #pragma unroll
      for (int kt = 0; kt < 8; ++kt)
        #pragma unroll
        for (int r = 0; r < 4; ++r) {
          int key = keyb + kt * 16 + g * 4 + r;
          float f = fk[key];
          float dm = (f - rc.x) * (rc.x * f);
          float s = ap_ * fmaxf(dm, 0.f) + an_ * fminf(dm, 0.f);
          float e = __expf(rc.y * S[kt][qt][r] + rc.z * s - rc.w);
          psum[qt] += e;
          S[kt][qt][r] = e;
        }
    }
    #pragma unroll
    for (int qt = 0; qt < 2; ++qt) {
      psum[qt] += __shfl_xor(psum[qt], 16);
      psum[qt] += __shfl_xor(psum[qt], 32);
      if (g == 0) sumP[wv][qt * 16 + c] = psum[qt];
    }
  }

  // ---- pack P A-fragments: frag p element e <-> key keyb + (2p+(e>>2))*16 + g*4 + (e&3)
  union AW { unsigned u[4]; bf16x8 v; };
  AW aw[2][4];
  #pragma unroll
  for (int qt = 0; qt < 2; ++qt)
    #pragma unroll
    for (int p = 0; p < 4; ++p)
      #pragma unroll
      for (int m = 0; m < 4; ++m) {
        int kt = 2 * p + (m >> 1), rp = (m & 1) * 2;
        aw[qt][p].u[m] = (unsigned)f2bf(S[kt][qt][rp]) |
                         ((unsigned)f2bf(S[kt][qt][rp + 1]) << 16);
      }

  // ---- PV: O[qt*16 + g*4 + r][dt*16 + c] accumulated cross-wave in Obuf ----
  #pragma unroll
  for (int dt = 0; dt < 4; ++dt) {
    const unsigned short* vrow =
        Vt + (size_t)(bh * 64 + dt * 16 + c) * 1024 + keyb + g * 4;
    union BV { ushort4 s[2]; bf16x8 v; };
    BV bv[4];
    #pragma unroll
    for (int p = 0; p < 4; ++p) {
      bv[p].s[0] = *(const ushort4*)(vrow + p * 32);        // keys (2p)*16 + g*4 + 0..3
      bv[p].s[1] = *(const ushort4*)(vrow + p * 32 + 16);   // keys (2p+1)*16 + g*4 + 0..3
    }
    #pragma unroll
    for (int qt = 0; qt < 2; ++qt) {
      f32x4 o = {0.f, 0.f, 0.f, 0.f};
      #pragma unroll
      for (int p = 0; p < 4; ++p)
        o = __builtin_amdgcn_mfma_f32_16x16x32_bf16(aw[qt][p].v, bv[p].v, o, 0, 0, 0);
      #pragma unroll
      for (int r = 0; r < 4; ++r)
        atomicAdd(&Obuf[qt * 16 + g * 4 + r][dt * 16 + c], o[r]);
    }
  }
  __syncthreads();
  if (tid < 32) {
    float s = 0.f;
    #pragma unroll
    for (int w = 0; w < 8; ++w) s += sumP[w][tid];
    rowRcp[tid] = 1.f / s;
  }
  __syncthreads();

  // ---- epilogue: normalize + store bf16 ----
  {
    int qi = tid >> 4, d0 = (tid & 15) * 4;
    float rcp = rowRcp[qi];
    float4 ov = *(const float4*)&Obuf[qi][d0];
    ushort4 pk;
    pk.x = f2bf(ov.x * rcp); pk.y = f2bf(ov.y * rcp);
    pk.z = f2bf(ov.z * rcp); pk.w = f2bf(ov.w * rcp);
    *(ushort4*)(attnO + (size_t)(b * 1024 + t0 + qi) * 512 + h * 64 + d0) = pk;
  }
}

extern "C" void kernel_launch(void* const* d_in, const int* in_sizes, int n_in,
                              void* d_out, int out_size, void* d_ws, size_t ws_size,
                              hipStream_t stream) {
  const float* q = (const float*)d_in[0];
  const float* k = (const float*)d_in[1];
  const float* v = (const float*)d_in[2];
  const float* frac = (const float*)d_in[3];
  const float* Wq = (const float*)d_in[4];
  const float* bq = (const float*)d_in[5];
  const float* Wk = (const float*)d_in[6];
  const float* bk = (const float*)d_in[7];
  const float* Wv = (const float*)d_in[8];
  const float* bv = (const float*)d_in[9];
  const float* Wo = (const float*)d_in[10];
  const float* bo = (const float*)d_in[11];
  const float* ap = (const float*)d_in[12];
  const float* an = (const float*)d_in[13];
  const float* gm = (const float*)d_in[14];
  const float* dl = (const float*)d_in[15];
  const int* afb = (const int*)d_in[16];

  char* ws = (char*)d_ws;
  unsigned short* qb = (unsigned short*)(ws + 0);
  unsigned short* kb = (unsigned short*)(ws + 8388608);
  unsigned short* vb = (unsigned short*)(ws + 16777216);
  unsigned short* wqT = (unsigned short*)(ws + 25165824);
  unsigned short* wkT = (unsigned short*)(ws + 25690112);
  unsigned short* wvT = (unsigned short*)(ws + 26214400);
  unsigned short* woT = (unsigned short*)(ws + 26738688);
  unsigned short* Qh = (unsigned short*)(ws + 27262976);
  unsigned short* Kh = (unsigned short*)(ws + 35651584);
  unsigned short* Vt = (unsigned short*)(ws + 44040192);
  unsigned short* aO = (unsigned short*)(ws + 52428800);
  float* fst = (float*)(ws + 60817408);

  cvt3_kernel<<<dim3(2048, 3), 256, 0, stream>>>(q, k, v, qb, kb, vb);
  wtrans4_kernel<<<dim3(16, 16, 4), 256, 0, stream>>>(Wq, Wk, Wv, Wo, wqT, wkT, wvT, woT);
  frac_stats_kernel<<<2048, 256, 0, stream>>>(frac, fst);
  gemm_kernel<0><<<dim3(4, 64), 256, 0, stream>>>(qb, wqT, bq, 0.125f, (void*)Qh);
  gemm_kernel<0><<<dim3(4, 64), 256, 0, stream>>>(kb, wkT, bk, 1.0f, (void*)Kh);
  gemm_kernel<1><<<dim3(4, 64), 256, 0, stream>>>(vb, wvT, bv, 1.0f, (void*)Vt);
  attn_kernel<<<dim3(2048), 512, 0, stream>>>(Qh, Kh, Vt, aO, frac, fst,
                                              ap, an, gm, dl, afb);
  gemm_kernel<2><<<dim3(4, 64), 256, 0, stream>>>(aO, woT, bo, 1.0f, d_out);
}